// Round 1
// baseline (111.103 us; speedup 1.0000x reference)
//
#include <hip/hip_runtime.h>

// Problem constants (match reference)
namespace {
constexpr int GH = 200, GW = 200, GD = 16;
constexpr int NV = GH * GW * GD;        // 640000 voxels
constexpr int NCLS = 18;                // output feature channels
constexpr int NF = 17;                  // per-gaussian feature channels (class 17 is zero)
constexpr int NG = 8192;
constexpr int KMAX = 10;                // static tile bound from reference
constexpr float VOX = 0.4f;
constexpr float LO0 = -40.f, LO1 = -40.f, LO2 = -1.f;
constexpr float HI0 = 40.f, HI1 = 40.f, HI2 = 5.4f;
constexpr float EPSV = 1e-6f;

constexpr int TILE_XY = 4;              // tile = 4x4x16 voxels
constexpr int NTX = GH / TILE_XY;       // 50
constexpr int NTY = GW / TILE_XY;       // 50
constexpr int NT = NTX * NTY;           // 2500 tiles
constexpr int REC_DW = 32;              // record: 32 dwords = 128 B (incl. box)
constexpr int REC_V4 = REC_DW / 4;      // 8 float4
constexpr int CAP = 128;                // per-tile capacity (avg ~16, >25 sigma)
constexpr int CH = 32;                  // entries staged per LDS chunk

constexpr float NHL2E = -0.72134752044448170368f;  // -0.5 * log2(e)
}

// ---------------------------------------------------------------------------
// Kernel A: one thread per gaussian. Bbox math is bit-identical to the
// reference (literal /0.4f, truncating casts, clip=min(max)). The full 128 B
// evaluation record is written INLINE into every overlapped tile's list —
// gather needs no indirection and stages contiguous memory.
// Record (floats): [0..2]=mean, [3]=opacity,
// [4]=s*a00 [5]=s*a11 [6]=s*a22 [7]=2s*a01 [8]=2s*a02 [9]=2s*a12 (s=-0.5*log2e)
// [10..26]=feats, [27..29]=il (int bits), [30]=sp pack (int bits), [31]=0
// ---------------------------------------------------------------------------
__global__ __launch_bounds__(64) void gv_bin(
    const float* __restrict__ means,   // [NG,3]
    const float* __restrict__ opac,    // [NG,1]
    const float* __restrict__ feats,   // [NG,17]
    const float* __restrict__ scales,  // [NG,3]
    const float* __restrict__ rots,    // [NG,4] wxyz
    int* __restrict__ counts,          // [NT], pre-zeroed
    float4* __restrict__ lists)        // [NT * CAP * REC_V4]
{
    const int g = blockIdx.x * blockDim.x + threadIdx.x;
    if (g >= NG) return;

    const float mx = means[g * 3 + 0];
    const float my = means[g * 3 + 1];
    const float mz = means[g * 3 + 2];
    const float sx = scales[g * 3 + 0];
    const float sy = scales[g * 3 + 1];
    const float sz = scales[g * 3 + 2];
    float qw = rots[g * 4 + 0];
    float qx = rots[g * 4 + 1];
    float qy = rots[g * 4 + 2];
    float qz = rots[g * 4 + 3];

    // normalized quaternion -> rotation matrix
    const float qn = rsqrtf(qw * qw + qx * qx + qy * qy + qz * qz);
    qw *= qn; qx *= qn; qy *= qn; qz *= qn;
    const float r00 = 1.f - 2.f * (qy * qy + qz * qz);
    const float r01 = 2.f * (qx * qy - qw * qz);
    const float r02 = 2.f * (qx * qz + qw * qy);
    const float r10 = 2.f * (qx * qy + qw * qz);
    const float r11 = 1.f - 2.f * (qx * qx + qz * qz);
    const float r12 = 2.f * (qy * qz - qw * qx);
    const float r20 = 2.f * (qx * qz - qw * qy);
    const float r21 = 2.f * (qy * qz + qw * qx);
    const float r22 = 1.f - 2.f * (qx * qx + qy * qy);

    const float s0 = sx * sx, s1 = sy * sy, s2 = sz * sz;
    const float c00 = r00 * r00 * s0 + r01 * r01 * s1 + r02 * r02 * s2;
    const float c11 = r10 * r10 * s0 + r11 * r11 * s1 + r12 * r12 * s2;
    const float c22 = r20 * r20 * s0 + r21 * r21 * s1 + r22 * r22 * s2;
    const float i0 = 1.f / s0, i1 = 1.f / s1, i2 = 1.f / s2;
    const float a00 = r00 * r00 * i0 + r01 * r01 * i1 + r02 * r02 * i2;
    const float a01 = r00 * r10 * i0 + r01 * r11 * i1 + r02 * r12 * i2;
    const float a02 = r00 * r20 * i0 + r01 * r21 * i1 + r02 * r22 * i2;
    const float a11 = r10 * r10 * i0 + r11 * r11 * i1 + r12 * r12 * i2;
    const float a12 = r10 * r20 * i0 + r11 * r21 * i1 + r12 * r22 * i2;
    const float a22 = r20 * r20 * i0 + r21 * r21 * i1 + r22 * r22 * i2;

    const float m3[3] = { mx, my, mz };
    const float sg[3] = { sqrtf(c00), sqrtf(c11), sqrtf(c22) };
    const float lo3[3] = { LO0, LO1, LO2 };
    const float hi3[3] = { HI0, HI1, HI2 };
    const int dims[3] = { GH, GW, GD };

    int il[3], sp[3];
    bool valid = true;
#pragma unroll
    for (int ax = 0; ax < 3; ++ax) {
        const float bl = fminf(fmaxf(m3[ax] - 3.f * sg[ax], lo3[ax]), hi3[ax]);
        const float bh = fminf(fmaxf(m3[ax] + 3.f * sg[ax], lo3[ax]), hi3[ax]);
        valid = valid &&
                (((bl > lo3[ax]) || (bh > lo3[ax])) && ((bl < hi3[ax]) || (bh < hi3[ax])));
        const int a = (int)((bl - lo3[ax]) / VOX);
        const int b = (int)((bh - lo3[ax]) / VOX);
        int s = b - a + 1;
        s = min(s, KMAX);             // reference's static K tile
        s = min(s, dims[ax] - a);     // vox < dims mask
        s = max(s, 0);
        il[ax] = a;
        sp[ax] = s;
    }

    if (!valid || sp[0] <= 0 || sp[1] <= 0 || sp[2] <= 0) return;
    const int pack = sp[0] | (sp[1] << 8) | (sp[2] << 16);

    const float* F = feats + (size_t)g * NF;
    float4 R[REC_V4];
    R[0] = make_float4(mx, my, mz, opac[g]);
    R[1] = make_float4(NHL2E * a00, NHL2E * a11, NHL2E * a22, 2.f * NHL2E * a01);
    R[2] = make_float4(2.f * NHL2E * a02, 2.f * NHL2E * a12, F[0], F[1]);
    R[3] = make_float4(F[2], F[3], F[4], F[5]);
    R[4] = make_float4(F[6], F[7], F[8], F[9]);
    R[5] = make_float4(F[10], F[11], F[12], F[13]);
    R[6] = make_float4(F[14], F[15], F[16], __int_as_float(il[0]));
    R[7] = make_float4(__int_as_float(il[1]), __int_as_float(il[2]),
                       __int_as_float(pack), 0.f);

    // scatter the record into overlapped tiles (<= 4x4 tiles)
    const int tx0 = il[0] / TILE_XY;
    const int tx1 = (il[0] + sp[0] - 1) / TILE_XY;
    const int ty0 = il[1] / TILE_XY;
    const int ty1 = (il[1] + sp[1] - 1) / TILE_XY;
    for (int tx = tx0; tx <= tx1; ++tx)
        for (int ty = ty0; ty <= ty1; ++ty) {
            const int tile = tx * NTY + ty;
            const int idx = atomicAdd(counts + tile, 1);
            if (idx < CAP) {
                float4* dst = lists + ((size_t)tile * CAP + idx) * REC_V4;
#pragma unroll
                for (int u = 0; u < REC_V4; ++u) dst[u] = R[u];
            }
        }
}

// ---------------------------------------------------------------------------
// Kernel B v2: FOUR waves (256 threads) per 4x4x16 tile; each thread owns ONE
// voxel. Thread t: vz = t&15, vy = (t>>4)&3, vx = t>>6 relative to the tile,
// so each wave covers 64 CONSECUTIVE output voxels (fully coalesced stores).
// Staging: 32 entries x 8 float4 = 256 float4 = exactly one float4 per
// thread -> one perfectly coalesced 4 KB round per chunk, double-buffered.
// 2500 blocks x 4 waves = 10000 waves (~10/SIMD) for latency hiding vs the
// previous 2.44/SIMD.
// ---------------------------------------------------------------------------
__global__ __launch_bounds__(256) void gv_gather(
    const int* __restrict__ counts,
    const float4* __restrict__ lists,
    const float* __restrict__ empty_scalar,
    float* __restrict__ out)           // [NV] density, then [NV,18] feats
{
    __shared__ float4 s_rec[2][CH * REC_V4];   // 2 x 32 x 128 B = 8 KB

    const int tile = blockIdx.x;
    const int tx = tile / NTY;
    const int ty = tile - tx * NTY;

    const int t = threadIdx.x;         // 0..255
    const int vz = t & 15;             // z within tile (tile spans full z)
    const int ly = (t >> 4) & 3;
    const int lx = t >> 6;             // == wave id; wave owns one x-row

    const int vx = tx * TILE_XY + lx;
    const int vy = ty * TILE_XY + ly;
    const float cx = ((float)vx + 0.5f) * VOX + LO0;
    const float cy = ((float)vy + 0.5f) * VOX + LO1;
    const float cz = ((float)vz + 0.5f) * VOX + LO2;

    const int n = min(counts[tile], CAP);
    const float4* __restrict__ tl = lists + (size_t)tile * CAP * REC_V4;

    float accd = 0.f;
    float accf[NF];
#pragma unroll
    for (int c = 0; c < NF; ++c) accf[c] = 0.f;

    // staging roles: thread t loads float4 #(t&7) of entry (t>>3) of the chunk
    const int e_ld = t >> 3;
    const int q_ld = t & 7;
    float4 r;

    const int nchunk = (n + CH - 1) / CH;
    int buf = 0;

    if (nchunk > 0 && e_ld < n) {
        s_rec[0][e_ld * REC_V4 + q_ld] = tl[(size_t)e_ld * REC_V4 + q_ld];
    }
    __syncthreads();

    for (int c = 0; c < nchunk; ++c) {
        // issue next chunk's coalesced loads before processing this one
        const int nidx = (c + 1) * CH + e_ld;
        const bool nact = (c + 1 < nchunk) && (nidx < n);
        if (nact) r = tl[(size_t)nidx * REC_V4 + q_ld];

        const int m = min(CH, n - c * CH);
        for (int e = 0; e < m; ++e) {
            const float4* E = &s_rec[buf][e * REC_V4];
            const float4 e6 = E[6], e7 = E[7];

            const int il0 = __float_as_int(e6.w);
            const int il1 = __float_as_int(e7.x);
            const int il2 = __float_as_int(e7.y);
            const int pk  = __float_as_int(e7.z);

            const bool in =
                ((unsigned)(vx - il0) < (unsigned)(pk & 255)) &
                ((unsigned)(vy - il1) < (unsigned)((pk >> 8) & 255)) &
                ((unsigned)(vz - il2) < (unsigned)((pk >> 16) & 255));

            // wave-uniform skip: entry's xy/z box misses this wave entirely
            if (!__any(in)) continue;

            const float4 e0 = E[0], e1 = E[1], e2 = E[2], e3 = E[3];
            const float4 e4 = E[4], e5 = E[5];

            const float dx = cx - e0.x;
            const float dy = cy - e0.y;
            const float dz = cz - e0.z;
            // pre-scaled exponent: ee = -0.5*log2e*maha, dens = op * 2^ee
            const float q0 = e1.x * dx * dx + e1.y * dy * dy + e1.w * dx * dy;
            const float q1 = e2.x * dx + e2.y * dy;
            const float ee = q0 + dz * (q1 + e1.z * dz);
            const float dens = e0.w * __builtin_amdgcn_exp2f(ee);

            if (in) {
                accd += dens;
                const float f[NF] = { e2.z, e2.w, e3.x, e3.y, e3.z, e3.w,
                                      e4.x, e4.y, e4.z, e4.w,
                                      e5.x, e5.y, e5.z, e5.w,
                                      e6.x, e6.y, e6.z };
#pragma unroll
                for (int cc = 0; cc < NF; ++cc) accf[cc] += dens * f[cc];
            }
        }

        if (nact) {
            s_rec[buf ^ 1][e_ld * REC_V4 + q_ld] = r;
        }
        __syncthreads();
        buf ^= 1;
    }

    // Epilogue: empty gaussian + normalize + store
    const float es = empty_scalar[0];
    const float ex = (cx - 0.5f * (LO0 + HI0)) / (HI0 - LO0);
    const float ey = (cy - 0.5f * (LO1 + HI1)) / (HI1 - LO1);
    const float ez = (cz - 0.5f * (LO2 + HI2)) / (HI2 - LO2);
    const float dev = __expf(-0.5f * (ex * ex + ey * ey + ez * ez));
    const float dsv = accd + dev;

    const int vidx = (vx * GW + vy) * GD + vz;   // 64 consecutive per wave
    out[vidx] = dsv;

    const float inv = 1.f / fmaxf(dsv, EPSV);
    float vals[NCLS];
#pragma unroll
    for (int c = 0; c < NF; ++c) vals[c] = accf[c] * inv;
    vals[NF] = dev * es * inv;

    float2* of2 = (float2*)(out + NV + (size_t)vidx * NCLS);  // 8B aligned
#pragma unroll
    for (int p = 0; p < NCLS / 2; ++p)
        of2[p] = make_float2(vals[2 * p], vals[2 * p + 1]);
}

extern "C" void kernel_launch(void* const* d_in, const int* in_sizes, int n_in,
                              void* d_out, int out_size, void* d_ws, size_t ws_size,
                              hipStream_t stream) {
    const float* means  = (const float*)d_in[0];
    const float* opac   = (const float*)d_in[1];
    const float* feats  = (const float*)d_in[2];
    const float* scales = (const float*)d_in[3];
    const float* rots   = (const float*)d_in[4];
    const float* esc    = (const float*)d_in[5];

    // workspace layout (16B-aligned): counts | lists (inline records)
    int*    counts = (int*)d_ws;                              // 10 KB
    float4* lists  = (float4*)((char*)d_ws + 64 * 1024);      // 2500*128*128B = 40 MB

    hipMemsetAsync(counts, 0, sizeof(int) * NT, stream);

    gv_bin<<<NG / 64, 64, 0, stream>>>(means, opac, feats, scales, rots,
                                       counts, lists);
    gv_gather<<<NT, 256, 0, stream>>>(counts, lists, esc, (float*)d_out);
}

// Round 3
// 104.980 us; speedup vs baseline: 1.0583x; 1.0583x over previous
//
#include <hip/hip_runtime.h>

// Problem constants (match reference)
namespace {
constexpr int GH = 200, GW = 200, GD = 16;
constexpr int NV = GH * GW * GD;        // 640000 voxels
constexpr int NCLS = 18;                // output feature channels
constexpr int NF = 17;                  // per-gaussian feature channels (class 17 is zero)
constexpr int NG = 8192;
constexpr int KMAX = 10;                // static tile bound from reference
constexpr float VOX = 0.4f;
constexpr float LO0 = -40.f, LO1 = -40.f, LO2 = -1.f;
constexpr float HI0 = 40.f, HI1 = 40.f, HI2 = 5.4f;
constexpr float EPSV = 1e-6f;

constexpr int TILE_XY = 4;              // tile = 4x4x16 voxels, one wave per tile
constexpr int NTX = GH / TILE_XY;       // 50
constexpr int NTY = GW / TILE_XY;       // 50
constexpr int NT = NTX * NTY;           // 2500 tiles
constexpr int REC_DW = 32;              // record: 32 dwords = 128 B (incl. box)
constexpr int REC_V4 = REC_DW / 4;      // 8 float4
constexpr int CAP = 128;                // per-tile capacity (avg ~17, >25 sigma)
constexpr int CH = 32;                  // entries staged per LDS chunk

constexpr float NHL2E = -0.72134752044448170368f;  // -0.5 * log2(e)

typedef float v2f __attribute__((ext_vector_type(2)));  // -> v_pk_fma_f32
}

// ---------------------------------------------------------------------------
// Kernel A: one thread per gaussian. Bbox math is bit-identical to the
// reference (literal /0.4f, truncating casts, clip=min(max)). The full 128 B
// evaluation record is written INLINE into every overlapped tile's list —
// gather needs no indirection and stages contiguous memory.
// Record (floats): [0..2]=mean, [3]=opacity,
// [4]=s*a00 [5]=s*a11 [6]=s*a22 [7]=2s*a01 [8]=2s*a02 [9]=2s*a12 (s=-0.5*log2e)
// [10..26]=feats, [27..29]=il (int bits), [30]=sp pack (int bits), [31]=0
// ---------------------------------------------------------------------------
__global__ __launch_bounds__(64) void gv_bin(
    const float* __restrict__ means,   // [NG,3]
    const float* __restrict__ opac,    // [NG,1]
    const float* __restrict__ feats,   // [NG,17]
    const float* __restrict__ scales,  // [NG,3]
    const float* __restrict__ rots,    // [NG,4] wxyz
    int* __restrict__ counts,          // [NT], pre-zeroed
    float4* __restrict__ lists)        // [NT * CAP * REC_V4]
{
    const int g = blockIdx.x * blockDim.x + threadIdx.x;
    if (g >= NG) return;

    const float mx = means[g * 3 + 0];
    const float my = means[g * 3 + 1];
    const float mz = means[g * 3 + 2];
    const float sx = scales[g * 3 + 0];
    const float sy = scales[g * 3 + 1];
    const float sz = scales[g * 3 + 2];
    float qw = rots[g * 4 + 0];
    float qx = rots[g * 4 + 1];
    float qy = rots[g * 4 + 2];
    float qz = rots[g * 4 + 3];

    // normalized quaternion -> rotation matrix
    const float qn = rsqrtf(qw * qw + qx * qx + qy * qy + qz * qz);
    qw *= qn; qx *= qn; qy *= qn; qz *= qn;
    const float r00 = 1.f - 2.f * (qy * qy + qz * qz);
    const float r01 = 2.f * (qx * qy - qw * qz);
    const float r02 = 2.f * (qx * qz + qw * qy);
    const float r10 = 2.f * (qx * qy + qw * qz);
    const float r11 = 1.f - 2.f * (qx * qx + qz * qz);
    const float r12 = 2.f * (qy * qz - qw * qx);
    const float r20 = 2.f * (qx * qz - qw * qy);
    const float r21 = 2.f * (qy * qz + qw * qx);
    const float r22 = 1.f - 2.f * (qx * qx + qy * qy);

    const float s0 = sx * sx, s1 = sy * sy, s2 = sz * sz;
    const float c00 = r00 * r00 * s0 + r01 * r01 * s1 + r02 * r02 * s2;
    const float c11 = r10 * r10 * s0 + r11 * r11 * s1 + r12 * r12 * s2;
    const float c22 = r20 * r20 * s0 + r21 * r21 * s1 + r22 * r22 * s2;
    const float i0 = 1.f / s0, i1 = 1.f / s1, i2 = 1.f / s2;
    const float a00 = r00 * r00 * i0 + r01 * r01 * i1 + r02 * r02 * i2;
    const float a01 = r00 * r10 * i0 + r01 * r11 * i1 + r02 * r12 * i2;
    const float a02 = r00 * r20 * i0 + r01 * r21 * i1 + r02 * r22 * i2;
    const float a11 = r10 * r10 * i0 + r11 * r11 * i1 + r12 * r12 * i2;
    const float a12 = r10 * r20 * i0 + r11 * r21 * i1 + r12 * r22 * i2;
    const float a22 = r20 * r20 * i0 + r21 * r21 * i1 + r22 * r22 * i2;

    const float m3[3] = { mx, my, mz };
    const float sg[3] = { sqrtf(c00), sqrtf(c11), sqrtf(c22) };
    const float lo3[3] = { LO0, LO1, LO2 };
    const float hi3[3] = { HI0, HI1, HI2 };
    const int dims[3] = { GH, GW, GD };

    int il[3], sp[3];
    bool valid = true;
#pragma unroll
    for (int ax = 0; ax < 3; ++ax) {
        const float bl = fminf(fmaxf(m3[ax] - 3.f * sg[ax], lo3[ax]), hi3[ax]);
        const float bh = fminf(fmaxf(m3[ax] + 3.f * sg[ax], lo3[ax]), hi3[ax]);
        valid = valid &&
                (((bl > lo3[ax]) || (bh > lo3[ax])) && ((bl < hi3[ax]) || (bh < hi3[ax])));
        const int a = (int)((bl - lo3[ax]) / VOX);
        const int b = (int)((bh - lo3[ax]) / VOX);
        int s = b - a + 1;
        s = min(s, KMAX);             // reference's static K tile
        s = min(s, dims[ax] - a);     // vox < dims mask
        s = max(s, 0);
        il[ax] = a;
        sp[ax] = s;
    }

    if (!valid || sp[0] <= 0 || sp[1] <= 0 || sp[2] <= 0) return;
    const int pack = sp[0] | (sp[1] << 8) | (sp[2] << 16);

    const float* F = feats + (size_t)g * NF;
    float4 R[REC_V4];
    R[0] = make_float4(mx, my, mz, opac[g]);
    R[1] = make_float4(NHL2E * a00, NHL2E * a11, NHL2E * a22, 2.f * NHL2E * a01);
    R[2] = make_float4(2.f * NHL2E * a02, 2.f * NHL2E * a12, F[0], F[1]);
    R[3] = make_float4(F[2], F[3], F[4], F[5]);
    R[4] = make_float4(F[6], F[7], F[8], F[9]);
    R[5] = make_float4(F[10], F[11], F[12], F[13]);
    R[6] = make_float4(F[14], F[15], F[16], __int_as_float(il[0]));
    R[7] = make_float4(__int_as_float(il[1]), __int_as_float(il[2]),
                       __int_as_float(pack), 0.f);

    // scatter the record into overlapped tiles (<= 4x4 tiles)
    const int tx0 = il[0] / TILE_XY;
    const int tx1 = (il[0] + sp[0] - 1) / TILE_XY;
    const int ty0 = il[1] / TILE_XY;
    const int ty1 = (il[1] + sp[1] - 1) / TILE_XY;
    for (int tx = tx0; tx <= tx1; ++tx)
        for (int ty = ty0; ty <= ty1; ++ty) {
            const int tile = tx * NTY + ty;
            const int idx = atomicAdd(counts + tile, 1);
            if (idx < CAP) {
                float4* dst = lists + ((size_t)tile * CAP + idx) * REC_V4;
#pragma unroll
                for (int u = 0; u < REC_V4; ++u) dst[u] = R[u];
            }
        }
}

// ---------------------------------------------------------------------------
// Kernel B (round-0 structure): ONE WAVE per 4x4x16 tile; each lane owns 4
// voxels along z, so entry decode + xy-quadratic are amortized 4x. The wave
// stages up to 32 inline records (contiguous 8 KB) from the tile's list to
// LDS in one coalesced round (2 lanes/entry x 4 dwordx4), double-buffered.
// NEW vs round-0: the 18-channel accumulate is restructured as 9 x packed
// float2 FMAs (v_pk_fma_f32) with a branchless dens select — masked entries
// contribute exactly +0.0, so numerics are unchanged.
// ---------------------------------------------------------------------------
__global__ __launch_bounds__(64) void gv_gather(
    const int* __restrict__ counts,
    const float4* __restrict__ lists,
    const float* __restrict__ empty_scalar,
    float* __restrict__ out)           // [NV] density, then [NV,18] feats
{
    __shared__ float4 s_rec[2][CH * REC_V4];   // 2 x 32 x 128 B = 8 KB

    const int tile = blockIdx.x;
    const int tx = tile / NTY;
    const int ty = tile - tx * NTY;

    const int lane = threadIdx.x;      // 0..63
    const int lx = lane >> 4;
    const int ly = (lane >> 2) & 3;
    const int vz0 = (lane & 3) << 2;   // z-group base: 0,4,8,12

    const int vx = tx * TILE_XY + lx;
    const int vy = ty * TILE_XY + ly;
    const float cx = ((float)vx + 0.5f) * VOX + LO0;
    const float cy = ((float)vy + 0.5f) * VOX + LO1;

    const int n = min(counts[tile], CAP);
    const float4* __restrict__ tl = lists + (size_t)tile * CAP * REC_V4;

    float accd[4] = { 0.f, 0.f, 0.f, 0.f };
    v2f accf[4][9];                    // 18 packed channels; [8].y is ch17 (==0 feats)
#pragma unroll
    for (int j = 0; j < 4; ++j)
#pragma unroll
        for (int c = 0; c < 9; ++c) accf[j][c] = (v2f)(0.f);

    // staging lane roles: entry e_ld = lane/2, half q_ld = lane&1 (64 B each)
    const int e_ld = lane >> 1;
    const int q_ld = lane & 1;
    float4 r0, r1, r2, r3;

    const int nchunk = (n + CH - 1) / CH;
    int buf = 0;

    if (nchunk > 0 && e_ld < n) {
        const float4* src = tl + (size_t)e_ld * REC_V4 + q_ld * 4;
        r0 = src[0]; r1 = src[1]; r2 = src[2]; r3 = src[3];
        float4* dst = &s_rec[0][e_ld * REC_V4 + q_ld * 4];
        dst[0] = r0; dst[1] = r1; dst[2] = r2; dst[3] = r3;
    }
    __syncthreads();

    for (int c = 0; c < nchunk; ++c) {
        // issue next chunk's coalesced loads before processing this one
        const int nidx = (c + 1) * CH + e_ld;
        const bool nact = (c + 1 < nchunk) && (nidx < n);
        if (nact) {
            const float4* src = tl + (size_t)nidx * REC_V4 + q_ld * 4;
            r0 = src[0]; r1 = src[1]; r2 = src[2]; r3 = src[3];
        }

        const int m = min(CH, n - c * CH);
        for (int e = 0; e < m; ++e) {
            const float4* E = &s_rec[buf][e * REC_V4];
            const float4 e0 = E[0], e1 = E[1], e2 = E[2], e3 = E[3];
            const float4 e4 = E[4], e5 = E[5], e6 = E[6], e7 = E[7];

            const int il0 = __float_as_int(e6.w);
            const int il1 = __float_as_int(e7.x);
            const int il2 = __float_as_int(e7.y);
            const int pk  = __float_as_int(e7.z);

            const bool inxy =
                ((unsigned)(vx - il0) < (unsigned)(pk & 255)) &
                ((unsigned)(vy - il1) < (unsigned)((pk >> 8) & 255));
            const unsigned spz = (unsigned)((pk >> 16) & 255);

            const float dx = cx - e0.x;
            const float dy = cy - e0.y;
            // pre-scaled exponent: ee = -0.5*log2e*maha, dens = op * 2^ee
            const float q0 = e1.x * dx * dx + e1.y * dy * dy + e1.w * dx * dy;
            const float q1 = e2.x * dx + e2.y * dy;
            const float A22 = e1.z;
            const float op = e0.w, mzv = e0.z;

            v2f f2[9];
            f2[0] = (v2f){ e2.z, e2.w };
            f2[1] = (v2f){ e3.x, e3.y };
            f2[2] = (v2f){ e3.z, e3.w };
            f2[3] = (v2f){ e4.x, e4.y };
            f2[4] = (v2f){ e4.z, e4.w };
            f2[5] = (v2f){ e5.x, e5.y };
            f2[6] = (v2f){ e5.z, e5.w };
            f2[7] = (v2f){ e6.x, e6.y };
            f2[8] = (v2f){ e6.z, 0.f };

#pragma unroll
            for (int j = 0; j < 4; ++j) {
                const float cz = ((float)(vz0 + j) + 0.5f) * VOX + LO2;
                const float dz = cz - mzv;
                const float ee = q0 + dz * (q1 + A22 * dz);
                const bool in = inxy & ((unsigned)(vz0 + j - il2) < spz);
                // branchless: masked entries contribute exactly +0.0
                const float dens = in ? op * __builtin_amdgcn_exp2f(ee) : 0.f;
                accd[j] += dens;
#pragma unroll
                for (int cc = 0; cc < 9; ++cc) accf[j][cc] += dens * f2[cc];
            }
        }

        if (nact) {
            float4* dst = &s_rec[buf ^ 1][e_ld * REC_V4 + q_ld * 4];
            dst[0] = r0; dst[1] = r1; dst[2] = r2; dst[3] = r3;
        }
        __syncthreads();
        buf ^= 1;
    }

    // Epilogue: empty gaussian + normalize + store
    const float es = empty_scalar[0];
    const float ex = (cx - 0.5f * (LO0 + HI0)) / (HI0 - LO0);
    const float ey = (cy - 0.5f * (LO1 + HI1)) / (HI1 - LO1);
    const float exy = ex * ex + ey * ey;

    float dsv[4], dev[4];
#pragma unroll
    for (int j = 0; j < 4; ++j) {
        const float cz = ((float)(vz0 + j) + 0.5f) * VOX + LO2;
        const float ez = (cz - 0.5f * (LO2 + HI2)) / (HI2 - LO2);
        dev[j] = __expf(-0.5f * (exy + ez * ez));
        dsv[j] = accd[j] + dev[j];
    }

    const int vbase = (vx * GW + vy) * GD + vz0;     // multiple of 4
    *(float4*)(out + vbase) = make_float4(dsv[0], dsv[1], dsv[2], dsv[3]);

#pragma unroll
    for (int j = 0; j < 4; ++j) {
        const float inv = 1.f / fmaxf(dsv[j], EPSV);
        float2* of2 = (float2*)(out + NV + (size_t)(vbase + j) * NCLS);  // 8B aligned
#pragma unroll
        for (int p = 0; p < 8; ++p)
            of2[p] = make_float2(accf[j][p].x * inv, accf[j][p].y * inv);
        of2[8] = make_float2(accf[j][8].x * inv, dev[j] * es * inv);
    }
}

extern "C" void kernel_launch(void* const* d_in, const int* in_sizes, int n_in,
                              void* d_out, int out_size, void* d_ws, size_t ws_size,
                              hipStream_t stream) {
    const float* means  = (const float*)d_in[0];
    const float* opac   = (const float*)d_in[1];
    const float* feats  = (const float*)d_in[2];
    const float* scales = (const float*)d_in[3];
    const float* rots   = (const float*)d_in[4];
    const float* esc    = (const float*)d_in[5];

    // workspace layout (16B-aligned): counts | lists (inline records)
    int*    counts = (int*)d_ws;                              // 10 KB
    float4* lists  = (float4*)((char*)d_ws + 64 * 1024);      // 2500*128*128B = 40 MB

    hipMemsetAsync(counts, 0, sizeof(int) * NT, stream);

    gv_bin<<<NG / 64, 64, 0, stream>>>(means, opac, feats, scales, rots,
                                       counts, lists);
    gv_gather<<<NT, 64, 0, stream>>>(counts, lists, esc, (float*)d_out);
}